// Round 1
// baseline (492.340 us; speedup 1.0000x reference)
//
#include <hip/hip_runtime.h>

// SWT inverse, dilation=1, circular padding, Haar-like 2-tap kernels.
// out[h,w] = 0.125 * ( A[w-1] + B[w] )  (indices mod 256), where
//   A = (LLp+LHp+HLp+HHp) + (LLc+LHc-HLc-HHc)   (p = row h-1, c = row h)
//   B = (LLp-LHp+HLp-HHp) + (LLc-LHc-HLc+HHc)
// Coefficient magnitude 0.25*(1/sqrt(2))^2 == 0.125 (exact to ~1e-8 rel;
// tolerance is 5.8e-2, so hardcoding is safe).

static constexpr int HH_ = 256;   // H
static constexpr int WW_ = 256;   // W
static constexpr int RPT = 16;    // rows per thread

__global__ __launch_bounds__(256) void swt_inv_kernel(
    const float* __restrict__ LL, const float* __restrict__ LH,
    const float* __restrict__ HL, const float* __restrict__ HH,
    float* __restrict__ out)
{
    // blockIdx.x = plane*4 + slab ; slab = 64 rows of one (b,c) plane
    const int slab  = blockIdx.x & 3;
    const int plane = blockIdx.x >> 2;
    const size_t poff = (size_t)plane * (HH_ * WW_);

    const int tx = threadIdx.x & 63;   // column group: 4 pixels
    const int ty = threadIdx.x >> 6;   // row strip within slab
    const int w  = tx << 2;
    const int wm = (w == 0) ? (WW_ - 1) : (w - 1);
    const int h0 = slab * 64 + ty * RPT;

    const float* ll = LL + poff;
    const float* lh = LH + poff;
    const float* hl = HL + poff;
    const float* hh = HH + poff;
    float* op = out + poff;

    // preload previous row (h0-1, wrapped)
    const int hp = (h0 == 0) ? (HH_ - 1) : (h0 - 1);
    const int rp = hp * WW_;

    float4 llp = *(const float4*)(ll + rp + w); float llpm = ll[rp + wm];
    float4 lhp = *(const float4*)(lh + rp + w); float lhpm = lh[rp + wm];
    float4 hlp = *(const float4*)(hl + rp + w); float hlpm = hl[rp + wm];
    float4 hhp = *(const float4*)(hh + rp + w); float hhpm = hh[rp + wm];

    #pragma unroll 4
    for (int i = 0; i < RPT; ++i) {
        const int rc = (h0 + i) * WW_;
        float4 llc = *(const float4*)(ll + rc + w); float llcm = ll[rc + wm];
        float4 lhc = *(const float4*)(lh + rc + w); float lhcm = lh[rc + wm];
        float4 hlc = *(const float4*)(hl + rc + w); float hlcm = hl[rc + wm];
        float4 hhc = *(const float4*)(hh + rc + w); float hhcm = hh[rc + wm];

        // left-tap combos (needed at columns wm, w, w+1, w+2)
        float Am = (llpm + lhpm + hlpm + hhpm) + (llcm + lhcm - hlcm - hhcm);
        float Ax = (llp.x + lhp.x + hlp.x + hhp.x) + (llc.x + lhc.x - hlc.x - hhc.x);
        float Ay = (llp.y + lhp.y + hlp.y + hhp.y) + (llc.y + lhc.y - hlc.y - hhc.y);
        float Az = (llp.z + lhp.z + hlp.z + hhp.z) + (llc.z + lhc.z - hlc.z - hhc.z);

        // center-tap combos (columns w..w+3)
        float Bx = (llp.x - lhp.x + hlp.x - hhp.x) + (llc.x - lhc.x - hlc.x + hhc.x);
        float By = (llp.y - lhp.y + hlp.y - hhp.y) + (llc.y - lhc.y - hlc.y + hhc.y);
        float Bz = (llp.z - lhp.z + hlp.z - hhp.z) + (llc.z - lhc.z - hlc.z + hhc.z);
        float Bw = (llp.w - lhp.w + hlp.w - hhp.w) + (llc.w - lhc.w - hlc.w + hhc.w);

        float4 o;
        o.x = 0.125f * (Am + Bx);
        o.y = 0.125f * (Ax + By);
        o.z = 0.125f * (Ay + Bz);
        o.w = 0.125f * (Az + Bw);
        *(float4*)(op + rc + w) = o;

        llp = llc; llpm = llcm;
        lhp = lhc; lhpm = lhcm;
        hlp = hlc; hlpm = hlcm;
        hhp = hhc; hhpm = hhcm;
    }
}

extern "C" void kernel_launch(void* const* d_in, const int* in_sizes, int n_in,
                              void* d_out, int out_size, void* d_ws, size_t ws_size,
                              hipStream_t stream) {
    const float* LL = (const float*)d_in[0];
    const float* LH = (const float*)d_in[1];
    const float* HL = (const float*)d_in[2];
    const float* HH = (const float*)d_in[3];
    float* out = (float*)d_out;

    const int planes = out_size / (HH_ * WW_);   // B*C = 512
    dim3 grid(planes * 4);                        // 4 slabs of 64 rows each
    dim3 block(256);
    swt_inv_kernel<<<grid, block, 0, stream>>>(LL, LH, HL, HH, out);
}